// Round 2
// baseline (275.995 us; speedup 1.0000x reference)
//
#include <hip/hip_runtime.h>
#include <stdint.h>

#define NB    64      // batch
#define NROI  6000    // proposals per image
#define KGT   100     // gt slots per image
#define NT    6100    // NROI + KGT
#define ROUT  256     // sampled rois per image
#define FGPER 64
#define BLOCK 512
#define NWAVE (BLOCK / 64)
#define NCHUNK ((NT + BLOCK - 1) / BLOCK)

__device__ __forceinline__ uint32_t rotl32(uint32_t v, int s) { return (v << s) | (v >> (32 - s)); }

// Exact replica of JAX threefry2x32 (20 rounds, key schedule per jax/_src/prng.py)
#define TFR(r) { x0 += x1; x1 = rotl32(x1, r); x1 ^= x0; }
__device__ __forceinline__ void tf2x32(uint32_t k0, uint32_t k1, uint32_t& x0, uint32_t& x1) {
  uint32_t k2 = k0 ^ k1 ^ 0x1BD11BDAu;
  x0 += k0; x1 += k1;
  TFR(13) TFR(15) TFR(26) TFR(6)
  x0 += k1; x1 += k2 + 1u;
  TFR(17) TFR(29) TFR(16) TFR(24)
  x0 += k2; x1 += k0 + 2u;
  TFR(13) TFR(15) TFR(26) TFR(6)
  x0 += k0; x1 += k1 + 3u;
  TFR(17) TFR(29) TFR(16) TFR(24)
  x0 += k1; x1 += k2 + 4u;
  TFR(13) TFR(15) TFR(26) TFR(6)
  x0 += k2; x1 += k0 + 5u;
}

// jax_threefry_partitionable=True (default since JAX 0.4.36):
// 32-bit random bits for flat index i = fold(TF(key, (hi32(i), lo32(i)))) = out0 ^ out1
__device__ __forceinline__ uint32_t tf_bits32(uint32_t k0, uint32_t k1, uint32_t idx) {
  uint32_t x0 = 0u, x1 = idx;
  tf2x32(k0, k1, x0, x1);
  return x0 ^ x1;
}

// JAX uniform [0,1): bitcast(bits>>9 | 0x3F800000) - 1.0
__device__ __forceinline__ float u01f(uint32_t bits) {
  return __uint_as_float((bits >> 9) | 0x3F800000u) - 1.0f;
}

// p-th (0-based) index t whose mask is FALSE, scanning ascending.
// mode 0: member = fg (m >= 0.5); mode 1: member = bg (0 <= m < 0.5).
// Reproduces the stable-argsort "2.0 padding" region of JAX's ordering.
__device__ int nth_non(const float* mv, int n, int mode) {
  int c = 0;
  for (int t = 0; t < NT; ++t) {
    float m = mv[t];
    bool member = (mode == 0) ? (m >= 0.5f) : ((m < 0.5f) && (m >= 0.0f));
    if (!member) { if (c == n) return t; ++c; }
  }
  return NT - 1;
}

__global__ __launch_bounds__(BLOCK) void ptl_kernel(
    const float* __restrict__ all_rois,   // [NB, NROI, 5]
    const float* __restrict__ gt_boxes,   // [NB, KGT, 5]
    const float* __restrict__ bmeans,     // [4]
    const float* __restrict__ bstds,      // [4]
    const float* __restrict__ binw,       // [4]
    float* __restrict__ out)              // rois|labels|targets|inside|outside
{
#pragma clang fp contract(off)
  __shared__ float s_gx1[KGT], s_gy1[KGT], s_gx2[KGT], s_gy2[KGT], s_glb[KGT], s_gar[KGT];
  __shared__ unsigned char s_gz[KGT];
  __shared__ float s_maxov[NT];
  __shared__ unsigned char s_asg[NT];
  __shared__ uint64_t s_key[NT];          // ((bits>>9) << 32) | t  -> stable sort key
  __shared__ unsigned short s_ford[NT];   // fg_order (rank -> roi index)
  __shared__ unsigned short s_bidx[NT];   // bg indices in ascending index order
  __shared__ int s_wf[NWAVE], s_wb[NWAVE];
  __shared__ int s_fgN, s_bgN;

  const int b = blockIdx.x;
  const int tid = threadIdx.x;

  // ---- load gt boxes, precompute area / zero flag (unfused IEEE f32) ----
  if (tid < KGT) {
    const float* g = gt_boxes + ((size_t)b * KGT + tid) * 5;
    float x1 = g[0], y1 = g[1], x2 = g[2], y2 = g[3];
    s_gx1[tid] = x1; s_gy1[tid] = y1; s_gx2[tid] = x2; s_gy2[tid] = y2; s_glb[tid] = g[4];
    float wg = __fadd_rn(__fadd_rn(x2, -x1), 1.0f);
    float hg = __fadd_rn(__fadd_rn(y2, -y1), 1.0f);
    s_gar[tid] = __fmul_rn(wg, hg);
    s_gz[tid] = (wg == 1.0f && hg == 1.0f) ? 1 : 0;
  }
  if (tid == 0) { s_fgN = 0; s_bgN = 0; }
  __syncthreads();

  // ---- phase 2: IoU max/argmax per roi (rois_all = [all_rois ; gt appended]) ----
  for (int t = tid; t < NT; t += BLOCK) {
    float x1, y1, x2, y2;
    if (t < NROI) {
      const float* p = all_rois + ((size_t)b * NROI + t) * 5;
      x1 = p[1]; y1 = p[2]; x2 = p[3]; y2 = p[4];
    } else {
      int k = t - NROI;
      x1 = s_gx1[k]; y1 = s_gy1[k]; x2 = s_gx2[k]; y2 = s_gy2[k];
    }
    float wr = __fadd_rn(__fadd_rn(x2, -x1), 1.0f);
    float hr = __fadd_rn(__fadd_rn(y2, -y1), 1.0f);
    float ar = __fmul_rn(wr, hr);
    bool rz = (wr == 1.0f && hr == 1.0f);
    float best = -2.0f; int bk = 0;
    for (int k = 0; k < KGT; ++k) {
      float iw = __fadd_rn(__fadd_rn(fminf(x2, s_gx2[k]), -fmaxf(x1, s_gx1[k])), 1.0f);
      iw = fmaxf(iw, 0.0f);
      float ih = __fadd_rn(__fadd_rn(fminf(y2, s_gy2[k]), -fmaxf(y1, s_gy1[k])), 1.0f);
      ih = fmaxf(ih, 0.0f);
      float inter = __fmul_rn(iw, ih);
      float ov = inter / __fadd_rn(__fadd_rn(ar, s_gar[k]), -inter);  // IEEE div
      ov = s_gz[k] ? 0.0f : ov;
      ov = rz ? -1.0f : ov;
      if (ov > best) { best = ov; bk = k; }   // strict > => first-occurrence argmax
    }
    s_maxov[t] = best;
    s_asg[t] = (unsigned char)bk;
  }

  // ---- per-image keys (partitionable threefry, JAX >= 0.4.36 default) ----
  // keys = split(key(42), 64): keys[b] = TF((0,42), (0,b)) full pair
  // kf,kb,kr = split(keys[b], 3): k_i = TF(keys[b], (0,i)) full pair
  uint32_t kk0 = 0u, kk1 = (uint32_t)b;
  tf2x32(0u, 42u, kk0, kk1);
  uint32_t kf0 = 0u, kf1 = 0u; tf2x32(kk0, kk1, kf0, kf1);
  uint32_t kb0 = 0u, kb1 = 1u; tf2x32(kk0, kk1, kb0, kb1);
  uint32_t kr0 = 0u, kr1 = 2u; tf2x32(kk0, kk1, kr0, kr1);
  __syncthreads();

  // ---- phase 3: ordered compaction of fg (with uniform bits) and bg lists ----
  for (int c = 0; c < NCHUNK; ++c) {
    int t = c * BLOCK + tid;
    bool in = (t < NT);
    float m = in ? s_maxov[t] : -2.0f;
    bool fg = in && (m >= 0.5f);
    bool bg = in && (m < 0.5f) && (m >= 0.0f);
    uint32_t ub = 0;
    if (fg) ub = tf_bits32(kf0, kf1, (uint32_t)t);   // uniform(kf, (6100,)) bits[t]
    unsigned long long mf = __ballot(fg);
    unsigned long long mb = __ballot(bg);
    int lane = tid & 63, wv = tid >> 6;
    if (lane == 0) { s_wf[wv] = __popcll(mf); s_wb[wv] = __popcll(mb); }
    __syncthreads();
    int pf = 0, pb = 0, totf = 0, totb = 0;
    for (int w = 0; w < NWAVE; ++w) {
      int a = s_wf[w], d = s_wb[w];
      if (w < wv) { pf += a; pb += d; }
      totf += a; totb += d;
    }
    unsigned long long lmask = (1ull << lane) - 1ull;
    if (fg) s_key[s_fgN + pf + __popcll(mf & lmask)] = (((uint64_t)(ub >> 9)) << 32) | (uint32_t)t;
    if (bg) s_bidx[s_bgN + pb + __popcll(mb & lmask)] = (unsigned short)t;
    __syncthreads();
    if (tid == 0) { s_fgN += totf; s_bgN += totb; }
    __syncthreads();
  }
  const int F = s_fgN, Bc = s_bgN;

  // ---- phase 4: stable rank of fg keys (float-order then index; keys distinct) ----
  for (int i = tid; i < F; i += BLOCK) {
    uint64_t ki = s_key[i];
    int r = 0;
    for (int j2 = 0; j2 < F; ++j2) r += (s_key[j2] < ki) ? 1 : 0;
    s_ford[r] = (unsigned short)(ki & 0xFFFFull);
  }
  __syncthreads();

  // ---- phase 5: sampling + bbox transform + output ----
  if (tid < ROUT) {
    const int j = tid;
    float rfg = u01f(tf_bits32(kr0, kr1, (uint32_t)j));   // uniform(kr,(R,))
    float rbg = u01f(tf_bits32(kb0, kb1, (uint32_t)j));   // uniform(kb,(R,))

    int fg_this = (Bc > 0) ? (F < FGPER ? F : FGPER) : ((F > 0) ? ROUT : 0);
    int keep; float lab;
    if (j < fg_this) {
      int p;
      if (j < F) { p = j; }
      else {
        p = (int)(__fmul_rn(rfg, (float)(F < 1 ? 1 : F)));  // trunc like astype(int32)
        if (p > NT - 1) p = NT - 1;
        if (p < 0) p = 0;
      }
      keep = (p < F) ? (int)s_ford[p] : nth_non(s_maxov, p - F, 0);
      lab = s_glb[s_asg[keep]];
    } else {
      int q = (int)(__fmul_rn(rbg, (float)(Bc < 1 ? 1 : Bc)));
      if (q > NT - 1) q = NT - 1;
      if (q < 0) q = 0;
      if (Bc > 0) keep = (q < Bc) ? (int)s_bidx[q] : nth_non(s_maxov, q - Bc, 1);
      else        keep = q;   // no bg: argsort of all-2.0 is identity, q==0
      lab = 0.0f;
    }

    float ex1, ey1, ex2, ey2;
    if (keep < NROI) {
      const float* p = all_rois + ((size_t)b * NROI + keep) * 5;
      ex1 = p[1]; ey1 = p[2]; ex2 = p[3]; ey2 = p[4];
    } else {
      int k = keep - NROI;
      ex1 = s_gx1[k]; ey1 = s_gy1[k]; ex2 = s_gx2[k]; ey2 = s_gy2[k];
    }
    int ga = s_asg[keep];
    float gx1 = s_gx1[ga], gy1 = s_gy1[ga], gx2 = s_gx2[ga], gy2 = s_gy2[ga];

    float ew = ex2 - ex1 + 1.0f, eh = ey2 - ey1 + 1.0f;
    float ecx = ex1 + 0.5f * ew, ecy = ey1 + 0.5f * eh;
    float gw = gx2 - gx1 + 1.0f, gh = gy2 - gy1 + 1.0f;
    float gcx = gx1 + 0.5f * gw, gcy = gy1 + 0.5f * gh;
    float tt[4];
    tt[0] = (gcx - ecx) / ew;
    tt[1] = (gcy - ecy) / eh;
    tt[2] = logf(gw / ew);
    tt[3] = logf(gh / eh);
    bool isfg = (lab > 0.0f);

    size_t roff = (size_t)b * ROUT + j;
    float* po = out + roff * 5;
    po[0] = (float)b; po[1] = ex1; po[2] = ey1; po[3] = ex2; po[4] = ey2;
    out[(size_t)NB * ROUT * 5 + roff] = lab;
    float* pt = out + (size_t)NB * ROUT * 6 + roff * 4;
    float* pi = out + (size_t)NB * ROUT * 10 + roff * 4;
    float* pq = out + (size_t)NB * ROUT * 14 + roff * 4;
    for (int c = 0; c < 4; ++c) {
      float tn = (tt[c] - bmeans[c]) / bstds[c];
      float vi = isfg ? binw[c] : 0.0f;
      pt[c] = isfg ? tn : 0.0f;
      pi[c] = vi;
      pq[c] = (vi > 0.0f) ? 1.0f : 0.0f;
    }
  }
}

extern "C" void kernel_launch(void* const* d_in, const int* in_sizes, int n_in,
                              void* d_out, int out_size, void* d_ws, size_t ws_size,
                              hipStream_t stream) {
  const float* all_rois = (const float*)d_in[0];
  const float* gt_boxes = (const float*)d_in[1];
  // d_in[2] = num_boxes (unused, as in the reference)
  const float* bmeans = (const float*)d_in[3];
  const float* bstds  = (const float*)d_in[4];
  const float* binw   = (const float*)d_in[5];
  float* out = (float*)d_out;
  ptl_kernel<<<dim3(NB), dim3(BLOCK), 0, stream>>>(all_rois, gt_boxes, bmeans, bstds, binw, out);
}

// Round 4
// 144.953 us; speedup vs baseline: 1.9040x; 1.9040x over previous
//
#include <hip/hip_runtime.h>
#include <stdint.h>

#define NB    64      // batch
#define NROI  6000    // proposals per image
#define KGT   100     // gt slots per image
#define NT    6100    // NROI + KGT
#define ROUT  256     // sampled rois per image
#define FGPER 64

#define BLOCKA 256
#define NCHA   ((NT + BLOCKA - 1) / BLOCKA)   // 24 chunks per image

#define BLOCK 512
#define NWAVE (BLOCK / 64)
#define NCHUNK ((NT + BLOCK - 1) / BLOCK)

__device__ __forceinline__ uint32_t rotl32(uint32_t v, int s) { return (v << s) | (v >> (32 - s)); }

// Exact replica of JAX threefry2x32 (20 rounds, key schedule per jax/_src/prng.py)
#define TFR(r) { x0 += x1; x1 = rotl32(x1, r); x1 ^= x0; }
__device__ __forceinline__ void tf2x32(uint32_t k0, uint32_t k1, uint32_t& x0, uint32_t& x1) {
  uint32_t k2 = k0 ^ k1 ^ 0x1BD11BDAu;
  x0 += k0; x1 += k1;
  TFR(13) TFR(15) TFR(26) TFR(6)
  x0 += k1; x1 += k2 + 1u;
  TFR(17) TFR(29) TFR(16) TFR(24)
  x0 += k2; x1 += k0 + 2u;
  TFR(13) TFR(15) TFR(26) TFR(6)
  x0 += k0; x1 += k1 + 3u;
  TFR(17) TFR(29) TFR(16) TFR(24)
  x0 += k1; x1 += k2 + 4u;
  TFR(13) TFR(15) TFR(26) TFR(6)
  x0 += k2; x1 += k0 + 5u;
}

// jax_threefry_partitionable=True (default since JAX 0.4.36):
// bits for flat index i = fold(TF(key, (hi32(i), lo32(i)))) = out0 ^ out1
__device__ __forceinline__ uint32_t tf_bits32(uint32_t k0, uint32_t k1, uint32_t idx) {
  uint32_t x0 = 0u, x1 = idx;
  tf2x32(k0, k1, x0, x1);
  return x0 ^ x1;
}

// JAX uniform [0,1): bitcast(bits>>9 | 0x3F800000) - 1.0
__device__ __forceinline__ float u01f(uint32_t bits) {
  return __uint_as_float((bits >> 9) | 0x3F800000u) - 1.0f;
}

// ============================ kernel A: IoU max/argmax ============================
// grid (NCHA, NB) x BLOCKA. Writes max_ov[b][t] (f32) and gt_assign[b][t] (u8) to ws.
__global__ __launch_bounds__(BLOCKA) void iou_kernel(
    const float* __restrict__ all_rois,   // [NB, NROI, 5]
    const float* __restrict__ gt_boxes,   // [NB, KGT, 5]
    float* __restrict__ maxov_ws,         // [NB, NT]
    unsigned char* __restrict__ asg_ws)   // [NB, NT]
{
#pragma clang fp contract(off)
  __shared__ float s_gx1[KGT], s_gy1[KGT], s_gx2[KGT], s_gy2[KGT], s_gar[KGT];
  __shared__ unsigned char s_gz[KGT];
  __shared__ short s_vk[KGT];
  __shared__ int s_V, s_minz;

  const int b = blockIdx.y;
  const int tid = threadIdx.x;

  if (tid < KGT) {
    const float* g = gt_boxes + ((size_t)b * KGT + tid) * 5;
    float x1 = g[0], y1 = g[1], x2 = g[2], y2 = g[3];
    s_gx1[tid] = x1; s_gy1[tid] = y1; s_gx2[tid] = x2; s_gy2[tid] = y2;
    float wg = __fadd_rn(__fadd_rn(x2, -x1), 1.0f);
    float hg = __fadd_rn(__fadd_rn(y2, -y1), 1.0f);
    s_gar[tid] = __fmul_rn(wg, hg);
    s_gz[tid] = (wg == 1.0f && hg == 1.0f) ? 1 : 0;
  }
  __syncthreads();
  if (tid == 0) {
    int v = 0, mz = -1;
    for (int k = 0; k < KGT; ++k) {
      if (s_gz[k]) { if (mz < 0) mz = k; }
      else s_vk[v++] = (short)k;
    }
    s_V = v; s_minz = mz;
  }
  __syncthreads();
  const int V = s_V, minz = s_minz;

  const int t = blockIdx.x * BLOCKA + tid;
  if (t >= NT) return;

  float x1, y1, x2, y2;
  if (t < NROI) {
    const float* p = all_rois + ((size_t)b * NROI + t) * 5;
    x1 = p[1]; y1 = p[2]; x2 = p[3]; y2 = p[4];
  } else {
    int k = t - NROI;
    x1 = s_gx1[k]; y1 = s_gy1[k]; x2 = s_gx2[k]; y2 = s_gy2[k];
  }
  float wr = __fadd_rn(__fadd_rn(x2, -x1), 1.0f);
  float hr = __fadd_rn(__fadd_rn(y2, -y1), 1.0f);
  float ar = __fmul_rn(wr, hr);
  bool rz = (wr == 1.0f && hr == 1.0f);

  float best; int bk;
  if (rz) {
    best = -1.0f; bk = 0;   // all entries -1 -> argmax = 0
  } else {
    best = -2.0f; bk = 0;
    for (int v = 0; v < V; ++v) {
      int k = s_vk[v];
      float iw = __fadd_rn(__fadd_rn(fminf(x2, s_gx2[k]), -fmaxf(x1, s_gx1[k])), 1.0f);
      iw = fmaxf(iw, 0.0f);
      float ih = __fadd_rn(__fadd_rn(fminf(y2, s_gy2[k]), -fmaxf(y1, s_gy1[k])), 1.0f);
      ih = fmaxf(ih, 0.0f);
      float inter = __fmul_rn(iw, ih);
      float ov = inter / __fadd_rn(__fadd_rn(ar, s_gar[k]), -inter);  // IEEE div
      if (ov > best) { best = ov; bk = k; }   // strict > => first-occurrence argmax
    }
    // fold in the zero-gt rows (exact value 0.0 at indices >= minz)
    if (best < 0.0f) { best = 0.0f; bk = (minz >= 0 ? minz : 0); }        // V == 0 case
    else if (best == 0.0f && minz >= 0 && minz < bk) bk = minz;           // first-occurrence tie
  }
  maxov_ws[(size_t)b * NT + t] = best;
  asg_ws[(size_t)b * NT + t] = (unsigned char)bk;
}

// p-th (0-based) index t whose mask is FALSE, scanning ascending (argsort 2.0-pad region).
__device__ int nth_non(const float* mv, int n, int mode) {
  int c = 0;
  for (int t = 0; t < NT; ++t) {
    float m = mv[t];
    bool member = (mode == 0) ? (m >= 0.5f) : ((m < 0.5f) && (m >= 0.0f));
    if (!member) { if (c == n) return t; ++c; }
  }
  return NT - 1;
}

// ====================== kernel B: compaction + rank + sampling ======================
__global__ __launch_bounds__(BLOCK) void sample_kernel(
    const float* __restrict__ all_rois,
    const float* __restrict__ gt_boxes,
    const float* __restrict__ maxov_ws,
    const unsigned char* __restrict__ asg_ws,
    const float* __restrict__ bmeans,
    const float* __restrict__ bstds,
    const float* __restrict__ binw,
    float* __restrict__ out)
{
#pragma clang fp contract(off)
  __shared__ float s_gx1[KGT], s_gy1[KGT], s_gx2[KGT], s_gy2[KGT], s_glb[KGT];
  __shared__ float s_maxov[NT];
  __shared__ unsigned char s_asg[NT];
  __shared__ uint64_t s_key[NT];
  __shared__ unsigned short s_ford[NT];
  __shared__ unsigned short s_bidx[NT];
  __shared__ int s_wf[NWAVE], s_wb[NWAVE];
  __shared__ int s_fgN, s_bgN;

  const int b = blockIdx.x;
  const int tid = threadIdx.x;

  if (tid < KGT) {
    const float* g = gt_boxes + ((size_t)b * KGT + tid) * 5;
    s_gx1[tid] = g[0]; s_gy1[tid] = g[1]; s_gx2[tid] = g[2]; s_gy2[tid] = g[3]; s_glb[tid] = g[4];
  }
  if (tid == 0) { s_fgN = 0; s_bgN = 0; }
  for (int t = tid; t < NT; t += BLOCK) {
    s_maxov[t] = maxov_ws[(size_t)b * NT + t];
    s_asg[t] = asg_ws[(size_t)b * NT + t];
  }

  // per-image keys (partitionable threefry):
  // keys[b] = TF((0,42),(0,b)); kf,kb,kr = TF(keys[b],(0,{0,1,2}))
  uint32_t kk0 = 0u, kk1 = (uint32_t)b;
  tf2x32(0u, 42u, kk0, kk1);
  uint32_t kf0 = 0u, kf1 = 0u; tf2x32(kk0, kk1, kf0, kf1);
  uint32_t kb0 = 0u, kb1 = 1u; tf2x32(kk0, kk1, kb0, kb1);
  uint32_t kr0 = 0u, kr1 = 2u; tf2x32(kk0, kk1, kr0, kr1);
  __syncthreads();

  // ---- ordered compaction of fg (with uniform bits) and bg lists ----
  for (int c = 0; c < NCHUNK; ++c) {
    int t = c * BLOCK + tid;
    bool in = (t < NT);
    float m = in ? s_maxov[t] : -2.0f;
    bool fg = in && (m >= 0.5f);
    bool bg = in && (m < 0.5f) && (m >= 0.0f);
    uint32_t ub = 0;
    if (fg) ub = tf_bits32(kf0, kf1, (uint32_t)t);   // uniform(kf,(NT,)) bits[t]
    unsigned long long mf = __ballot(fg);
    unsigned long long mb = __ballot(bg);
    int lane = tid & 63, wv = tid >> 6;
    if (lane == 0) { s_wf[wv] = __popcll(mf); s_wb[wv] = __popcll(mb); }
    __syncthreads();
    int pf = 0, pb = 0, totf = 0, totb = 0;
    for (int w = 0; w < NWAVE; ++w) {
      int a = s_wf[w], d = s_wb[w];
      if (w < wv) { pf += a; pb += d; }
      totf += a; totb += d;
    }
    unsigned long long lmask = (1ull << lane) - 1ull;
    if (fg) s_key[s_fgN + pf + __popcll(mf & lmask)] = (((uint64_t)(ub >> 9)) << 32) | (uint32_t)t;
    if (bg) s_bidx[s_bgN + pb + __popcll(mb & lmask)] = (unsigned short)t;
    __syncthreads();
    if (tid == 0) { s_fgN += totf; s_bgN += totb; }
    __syncthreads();
  }
  const int F = s_fgN, Bc = s_bgN;

  // ---- stable rank of fg keys (float-order then index; keys distinct) ----
  for (int i = tid; i < F; i += BLOCK) {
    uint64_t ki = s_key[i];
    int r = 0;
    for (int j2 = 0; j2 < F; ++j2) r += (s_key[j2] < ki) ? 1 : 0;
    s_ford[r] = (unsigned short)(ki & 0xFFFFull);
  }
  __syncthreads();

  // ---- sampling + bbox transform + output ----
  if (tid < ROUT) {
    const int j = tid;
    float rfg = u01f(tf_bits32(kr0, kr1, (uint32_t)j));   // uniform(kr,(R,))
    float rbg = u01f(tf_bits32(kb0, kb1, (uint32_t)j));   // uniform(kb,(R,))

    int fg_this = (Bc > 0) ? (F < FGPER ? F : FGPER) : ((F > 0) ? ROUT : 0);
    int keep; float lab;
    if (j < fg_this) {
      int p;
      if (j < F) { p = j; }
      else {
        p = (int)(__fmul_rn(rfg, (float)(F < 1 ? 1 : F)));  // trunc like astype(int32)
        if (p > NT - 1) p = NT - 1;
        if (p < 0) p = 0;
      }
      keep = (p < F) ? (int)s_ford[p] : nth_non(s_maxov, p - F, 0);
      lab = s_glb[s_asg[keep]];
    } else {
      int q = (int)(__fmul_rn(rbg, (float)(Bc < 1 ? 1 : Bc)));
      if (q > NT - 1) q = NT - 1;
      if (q < 0) q = 0;
      if (Bc > 0) keep = (q < Bc) ? (int)s_bidx[q] : nth_non(s_maxov, q - Bc, 1);
      else        keep = q;   // no bg: argsort of all-2.0 is identity
      lab = 0.0f;
    }

    float ex1, ey1, ex2, ey2;
    if (keep < NROI) {
      const float* p = all_rois + ((size_t)b * NROI + keep) * 5;
      ex1 = p[1]; ey1 = p[2]; ex2 = p[3]; ey2 = p[4];
    } else {
      int k = keep - NROI;
      ex1 = s_gx1[k]; ey1 = s_gy1[k]; ex2 = s_gx2[k]; ey2 = s_gy2[k];
    }
    int ga = s_asg[keep];
    float gx1 = s_gx1[ga], gy1 = s_gy1[ga], gx2 = s_gx2[ga], gy2 = s_gy2[ga];

    float ew = ex2 - ex1 + 1.0f, eh = ey2 - ey1 + 1.0f;
    float ecx = ex1 + 0.5f * ew, ecy = ey1 + 0.5f * eh;
    float gw = gx2 - gx1 + 1.0f, gh = gy2 - gy1 + 1.0f;
    float gcx = gx1 + 0.5f * gw, gcy = gy1 + 0.5f * gh;
    float tt[4];
    tt[0] = (gcx - ecx) / ew;
    tt[1] = (gcy - ecy) / eh;
    tt[2] = logf(gw / ew);
    tt[3] = logf(gh / eh);
    bool isfg = (lab > 0.0f);

    size_t roff = (size_t)b * ROUT + j;
    float* po = out + roff * 5;
    po[0] = (float)b; po[1] = ex1; po[2] = ey1; po[3] = ex2; po[4] = ey2;
    out[(size_t)NB * ROUT * 5 + roff] = lab;
    float* pt = out + (size_t)NB * ROUT * 6 + roff * 4;
    float* pi = out + (size_t)NB * ROUT * 10 + roff * 4;
    float* pq = out + (size_t)NB * ROUT * 14 + roff * 4;
    for (int c = 0; c < 4; ++c) {
      float tn = (tt[c] - bmeans[c]) / bstds[c];
      float vi = isfg ? binw[c] : 0.0f;
      pt[c] = isfg ? tn : 0.0f;
      pi[c] = vi;
      pq[c] = (vi > 0.0f) ? 1.0f : 0.0f;
    }
  }
}

extern "C" void kernel_launch(void* const* d_in, const int* in_sizes, int n_in,
                              void* d_out, int out_size, void* d_ws, size_t ws_size,
                              hipStream_t stream) {
  const float* all_rois = (const float*)d_in[0];
  const float* gt_boxes = (const float*)d_in[1];
  // d_in[2] = num_boxes (unused, as in the reference)
  const float* bmeans = (const float*)d_in[3];
  const float* bstds  = (const float*)d_in[4];
  const float* binw   = (const float*)d_in[5];
  float* out = (float*)d_out;

  float* maxov_ws = (float*)d_ws;                              // NB*NT floats
  unsigned char* asg_ws = (unsigned char*)(maxov_ws + (size_t)NB * NT);  // NB*NT bytes

  iou_kernel<<<dim3(NCHA, NB), dim3(BLOCKA), 0, stream>>>(all_rois, gt_boxes, maxov_ws, asg_ws);
  sample_kernel<<<dim3(NB), dim3(BLOCK), 0, stream>>>(all_rois, gt_boxes, maxov_ws, asg_ws,
                                                      bmeans, bstds, binw, out);
}

// Round 6
// 115.386 us; speedup vs baseline: 2.3919x; 1.2562x over previous
//
#include <hip/hip_runtime.h>
#include <stdint.h>

#define NB    64      // batch
#define NROI  6000    // proposals per image
#define KGT   100     // gt slots per image
#define NT    6100    // NROI + KGT
#define ROUT  256     // sampled rois per image
#define FGPER 64

#define BLOCKA 256                      // iou block
#define ROIS_PER_BLOCK (BLOCKA * 2)     // 2 rois per thread
#define NCHA ((NT + ROIS_PER_BLOCK - 1) / ROIS_PER_BLOCK)   // 12

#define BLOCK 512
#define NWAVE (BLOCK / 64)
#define SEG 96                 // ceil(6100/64) = 96 segments of 64
#define SEGW (SEG / NWAVE)     // 12 segments per wave
#define CANDMAX 128

__device__ __forceinline__ uint32_t rotl32(uint32_t v, int s) { return (v << s) | (v >> (32 - s)); }

// Exact replica of JAX threefry2x32 (20 rounds)
#define TFR(r) { x0 += x1; x1 = rotl32(x1, r); x1 ^= x0; }
__device__ __forceinline__ void tf2x32(uint32_t k0, uint32_t k1, uint32_t& x0, uint32_t& x1) {
  uint32_t k2 = k0 ^ k1 ^ 0x1BD11BDAu;
  x0 += k0; x1 += k1;
  TFR(13) TFR(15) TFR(26) TFR(6)
  x0 += k1; x1 += k2 + 1u;
  TFR(17) TFR(29) TFR(16) TFR(24)
  x0 += k2; x1 += k0 + 2u;
  TFR(13) TFR(15) TFR(26) TFR(6)
  x0 += k0; x1 += k1 + 3u;
  TFR(17) TFR(29) TFR(16) TFR(24)
  x0 += k1; x1 += k2 + 4u;
  TFR(13) TFR(15) TFR(26) TFR(6)
  x0 += k2; x1 += k0 + 5u;
}

// jax_threefry_partitionable=True (default since JAX 0.4.36):
// bits for flat index i = fold(TF(key, (0, i))) = out0 ^ out1
__device__ __forceinline__ uint32_t tf_bits32(uint32_t k0, uint32_t k1, uint32_t idx) {
  uint32_t x0 = 0u, x1 = idx;
  tf2x32(k0, k1, x0, x1);
  return x0 ^ x1;
}

// JAX uniform [0,1): bitcast(bits>>9 | 0x3F800000) - 1.0
__device__ __forceinline__ float u01f(uint32_t bits) {
  return __uint_as_float((bits >> 9) | 0x3F800000u) - 1.0f;
}

// ============================ kernel A: IoU max/argmax ============================
// grid (NCHA, NB) x BLOCKA, 2 rois/thread. Writes max_ov (f32) + gt_assign (u8) to ws.
__global__ __launch_bounds__(BLOCKA) void iou_kernel(
    const float* __restrict__ all_rois,   // [NB, NROI, 5]
    const float* __restrict__ gt_boxes,   // [NB, KGT, 5]
    float* __restrict__ maxov_ws,         // [NB, NT]
    unsigned char* __restrict__ asg_ws)   // [NB, NT]
{
#pragma clang fp contract(off)
  __shared__ float s_gx1[KGT], s_gy1[KGT], s_gx2[KGT], s_gy2[KGT];   // original order (appended rois)
  __shared__ float s_cx1[KGT], s_cy1[KGT], s_cx2[KGT], s_cy2[KGT], s_car[KGT];  // compacted valid
  __shared__ short s_ck[KGT];
  __shared__ unsigned long long s_zm[2];
  __shared__ int s_V, s_minz;

  const int b = blockIdx.y;
  const int tid = threadIdx.x;
  const int lane = tid & 63, wv = tid >> 6;

  bool nz = false;
  float gx1v = 0, gy1v = 0, gx2v = 0, gy2v = 0, garv = 0;
  if (tid < KGT) {
    const float* g = gt_boxes + ((size_t)b * KGT + tid) * 5;
    gx1v = g[0]; gy1v = g[1]; gx2v = g[2]; gy2v = g[3];
    s_gx1[tid] = gx1v; s_gy1[tid] = gy1v; s_gx2[tid] = gx2v; s_gy2[tid] = gy2v;
    float wg = __fadd_rn(__fadd_rn(gx2v, -gx1v), 1.0f);
    float hg = __fadd_rn(__fadd_rn(gy2v, -gy1v), 1.0f);
    garv = __fmul_rn(wg, hg);
    nz = !(wg == 1.0f && hg == 1.0f);
  }
  if (wv < 2) {
    unsigned long long bm = __ballot(nz);
    if (lane == 0) s_zm[wv] = bm;
  }
  __syncthreads();
  if (tid == 0) {
    unsigned long long z0 = s_zm[0], z1 = s_zm[1];
    unsigned long long g0 = ~z0;                              // zero-rows among k=0..63
    unsigned long long g1 = (~z1) & ((1ull << (KGT - 64)) - 1ull); // k=64..99
    int mz = -1;
    if (g0) mz = __ffsll((long long)g0) - 1;
    else if (g1) mz = 64 + __ffsll((long long)g1) - 1;
    s_minz = mz;
    s_V = __popcll(z0) + __popcll(z1);
  }
  if (tid < KGT && nz) {
    unsigned long long lm = (1ull << lane) - 1ull;
    int pos = (wv == 0) ? __popcll(s_zm[0] & lm)
                        : __popcll(s_zm[0]) + __popcll(s_zm[1] & lm);
    s_cx1[pos] = gx1v; s_cy1[pos] = gy1v; s_cx2[pos] = gx2v; s_cy2[pos] = gy2v;
    s_car[pos] = garv; s_ck[pos] = (short)tid;
  }
  __syncthreads();
  const int V = s_V, minz = s_minz;

  const int base = blockIdx.x * ROIS_PER_BLOCK;
  const int t0 = base + tid, t1 = base + BLOCKA + tid;

  // load two rois (guarded)
  float x1a, y1a, x2a, y2a, x1b, y1b, x2b, y2b;
  {
    int ta = (t0 < NT) ? t0 : 0;
    if (ta < NROI) {
      const float* p = all_rois + ((size_t)b * NROI + ta) * 5;
      x1a = p[1]; y1a = p[2]; x2a = p[3]; y2a = p[4];
    } else {
      int k = ta - NROI;
      x1a = s_gx1[k]; y1a = s_gy1[k]; x2a = s_gx2[k]; y2a = s_gy2[k];
    }
    int tb = (t1 < NT) ? t1 : 0;
    if (tb < NROI) {
      const float* p = all_rois + ((size_t)b * NROI + tb) * 5;
      x1b = p[1]; y1b = p[2]; x2b = p[3]; y2b = p[4];
    } else {
      int k = tb - NROI;
      x1b = s_gx1[k]; y1b = s_gy1[k]; x2b = s_gx2[k]; y2b = s_gy2[k];
    }
  }
  float wra = __fadd_rn(__fadd_rn(x2a, -x1a), 1.0f);
  float hra = __fadd_rn(__fadd_rn(y2a, -y1a), 1.0f);
  float ara = __fmul_rn(wra, hra);
  bool rza = (wra == 1.0f && hra == 1.0f);
  float wrb = __fadd_rn(__fadd_rn(x2b, -x1b), 1.0f);
  float hrb = __fadd_rn(__fadd_rn(y2b, -y1b), 1.0f);
  float arb = __fmul_rn(wrb, hrb);
  bool rzb = (wrb == 1.0f && hrb == 1.0f);

  float besta = -2.0f, bestb = -2.0f;
  int bka = 0, bkb = 0;
  for (int v = 0; v < V; ++v) {
    float cx1 = s_cx1[v], cy1 = s_cy1[v], cx2 = s_cx2[v], cy2 = s_cy2[v], car = s_car[v];
    // roi a
    {
      float iw = __fadd_rn(__fadd_rn(fminf(x2a, cx2), -fmaxf(x1a, cx1)), 1.0f);
      iw = fmaxf(iw, 0.0f);
      float ih = __fadd_rn(__fadd_rn(fminf(y2a, cy2), -fmaxf(y1a, cy1)), 1.0f);
      ih = fmaxf(ih, 0.0f);
      float inter = __fmul_rn(iw, ih);
      float ov = inter / __fadd_rn(__fadd_rn(ara, car), -inter);  // IEEE div
      if (ov > besta) { besta = ov; bka = s_ck[v]; }
    }
    // roi b
    {
      float iw = __fadd_rn(__fadd_rn(fminf(x2b, cx2), -fmaxf(x1b, cx1)), 1.0f);
      iw = fmaxf(iw, 0.0f);
      float ih = __fadd_rn(__fadd_rn(fminf(y2b, cy2), -fmaxf(y1b, cy1)), 1.0f);
      ih = fmaxf(ih, 0.0f);
      float inter = __fmul_rn(iw, ih);
      float ov = inter / __fadd_rn(__fadd_rn(arb, car), -inter);
      if (ov > bestb) { bestb = ov; bkb = s_ck[v]; }
    }
  }
  // zero-gt fold (value exactly 0.0 at orig indices >= minz) + roi_zero override
  if (rza) { besta = -1.0f; bka = 0; }
  else {
    if (besta < 0.0f) { besta = 0.0f; bka = (minz >= 0 ? minz : 0); }
    else if (besta == 0.0f && minz >= 0 && minz < bka) bka = minz;
  }
  if (rzb) { bestb = -1.0f; bkb = 0; }
  else {
    if (bestb < 0.0f) { bestb = 0.0f; bkb = (minz >= 0 ? minz : 0); }
    else if (bestb == 0.0f && minz >= 0 && minz < bkb) bkb = minz;
  }
  if (t0 < NT) { maxov_ws[(size_t)b * NT + t0] = besta; asg_ws[(size_t)b * NT + t0] = (unsigned char)bka; }
  if (t1 < NT) { maxov_ws[(size_t)b * NT + t1] = bestb; asg_ws[(size_t)b * NT + t1] = (unsigned char)bkb; }
}

// p-th (0-based) index t whose mask is FALSE, ascending (argsort 2.0-pad region). Never hot.
__device__ int nth_non(const float* mv, int n, int mode) {
  int c = 0;
  for (int t = 0; t < NT; ++t) {
    float m = mv[t];
    bool member = (mode == 0) ? (m >= 0.5f) : ((m < 0.5f) && (m >= 0.0f));
    if (!member) { if (c == n) return t; ++c; }
  }
  return NT - 1;
}

// ====================== kernel B: compaction + select + sampling ======================
__global__ __launch_bounds__(BLOCK) void sample_kernel(
    const float* __restrict__ all_rois,
    const float* __restrict__ gt_boxes,
    const float* __restrict__ maxov_ws,
    const unsigned char* __restrict__ asg_ws,
    const float* __restrict__ bmeans,
    const float* __restrict__ bstds,
    const float* __restrict__ binw,
    float* __restrict__ out)
{
#pragma clang fp contract(off)
  __shared__ float s_gx1[KGT], s_gy1[KGT], s_gx2[KGT], s_gy2[KGT], s_glb[KGT];
  __shared__ uint64_t s_key[NT];            // fg keys, index-ordered
  __shared__ unsigned short s_bidx[NT];     // bg indices, ascending
  __shared__ unsigned short s_ford[NT];     // rank -> roi index (only r<64 used on hot path)
  __shared__ int s_cf[SEG], s_cb[SEG];
  __shared__ int s_pf[SEG + 1], s_pb[SEG + 1];
  __shared__ int s_hist[512];
  __shared__ int s_wtot[NWAVE];
  __shared__ uint64_t s_cand[CANDMAX];
  __shared__ int s_crank[CANDMAX];
  __shared__ int s_candN;

  const int b = blockIdx.x;
  const int tid = threadIdx.x;
  const int lane = tid & 63, wv = tid >> 6;
  const float* mvp = maxov_ws + (size_t)b * NT;
  const unsigned char* agp = asg_ws + (size_t)b * NT;

  if (tid < KGT) {
    const float* g = gt_boxes + ((size_t)b * KGT + tid) * 5;
    s_gx1[tid] = g[0]; s_gy1[tid] = g[1]; s_gx2[tid] = g[2]; s_gy2[tid] = g[3]; s_glb[tid] = g[4];
  }
  s_hist[tid] = 0;                      // BLOCK == 512 exactly
  if (tid < CANDMAX) s_crank[tid] = 0;
  if (tid == 0) s_candN = 0;

  // per-image keys (partitionable threefry):
  // keys[b] = TF((0,42),(0,b)); kf,kb,kr = TF(keys[b],(0,{0,1,2}))
  uint32_t kk0 = 0u, kk1 = (uint32_t)b;
  tf2x32(0u, 42u, kk0, kk1);
  uint32_t kf0 = 0u, kf1 = 0u; tf2x32(kk0, kk1, kf0, kf1);
  uint32_t kb0 = 0u, kb1 = 1u; tf2x32(kk0, kk1, kb0, kb1);
  uint32_t kr0 = 0u, kr1 = 2u; tf2x32(kk0, kk1, kr0, kr1);

  // ---- pass 1: per-segment fg/bg counts (no barriers inside) ----
  float m[SEGW];
  int fgbits = 0, bgbits = 0;
#pragma unroll
  for (int i = 0; i < SEGW; ++i) {
    int s = i * NWAVE + wv;
    int t = s * 64 + lane;
    float mv = (t < NT) ? mvp[t] : -2.0f;
    m[i] = mv;
    bool fg = (mv >= 0.5f);
    bool bg = (mv < 0.5f) && (mv >= 0.0f);
    unsigned long long bf = __ballot(fg), bb = __ballot(bg);
    if (lane == 0) { s_cf[s] = __popcll(bf); s_cb[s] = __popcll(bb); }
    fgbits |= fg ? (1 << i) : 0;
    bgbits |= bg ? (1 << i) : 0;
  }
  __syncthreads();

  // ---- pass 2: exclusive scan of segment counts (wave 0: fg, wave 1: bg) ----
  if (wv < 2) {
    int* src = (wv == 0) ? s_cf : s_cb;
    int* dst = (wv == 0) ? s_pf : s_pb;
    int v0 = src[lane];
    int v1 = (lane < SEG - 64) ? src[64 + lane] : 0;
    int x = v0;
    for (int off = 1; off < 64; off <<= 1) { int n = __shfl_up(x, off); if (lane >= off) x += n; }
    int tot0 = __shfl(x, 63);
    int y = v1;
    for (int off = 1; off < 32; off <<= 1) { int n = __shfl_up(y, off); if (lane >= off) y += n; }
    int tot96 = tot0 + __shfl(y, 31);
    dst[lane] = x - v0;
    if (lane < SEG - 64) dst[64 + lane] = tot0 + (y - v1);
    if (lane == 0) dst[SEG] = tot96;
  }
  __syncthreads();
  const int F = s_pf[SEG], Bc = s_pb[SEG];

  // ---- pass 3: positioned writes (fg keys with threefry bits; bg indices) ----
#pragma unroll
  for (int i = 0; i < SEGW; ++i) {
    int s = i * NWAVE + wv;
    int t = s * 64 + lane;
    bool fg = (fgbits >> i) & 1, bg = (bgbits >> i) & 1;
    unsigned long long bf = __ballot(fg), bb = __ballot(bg);
    unsigned long long lm = (1ull << lane) - 1ull;
    if (fg) {
      uint32_t ub = tf_bits32(kf0, kf1, (uint32_t)t);   // uniform(kf,(NT,)) bits[t]
      s_key[s_pf[s] + __popcll(bf & lm)] = (((uint64_t)(ub >> 9)) << 32) | (uint32_t)t;
    }
    if (bg) s_bidx[s_pb[s] + __popcll(bb & lm)] = (unsigned short)t;
  }
  __syncthreads();

  // ---- rank-select: only ranks < 64 are read when Bc>0 (always true here) ----
  if (Bc > 0) {
    // histogram on top-9 random bits (key bits 54..46)
    for (int i = tid; i < F; i += BLOCK)
      atomicAdd(&s_hist[(int)(s_key[i] >> 46) & 511], 1);
    __syncthreads();
    // exclusive scan of 512 buckets (8 waves of 64 + cross-wave offsets)
    int hv = s_hist[wv * 64 + lane];
    int hx = hv;
    for (int off = 1; off < 64; off <<= 1) { int n = __shfl_up(hx, off); if (lane >= off) hx += n; }
    if (lane == 63) s_wtot[wv] = hx;
    __syncthreads();
    int woff = 0;
    for (int w = 0; w < wv; ++w) woff += s_wtot[w];
    s_hist[wv * 64 + lane] = woff + hx - hv;   // in-place: now cum[bucket]
    __syncthreads();
    // candidates: keys in buckets with cum < 64
    for (int i = tid; i < F; i += BLOCK) {
      uint64_t k = s_key[i];
      if (s_hist[(int)(k >> 46) & 511] < FGPER) {
        int pos = atomicAdd(&s_candN, 1);
        if (pos < CANDMAX) s_cand[pos] = k;
      }
    }
    __syncthreads();
    int candN = s_candN;
    if (candN <= CANDMAX) {
      // exact global rank per candidate (4 threads per candidate)
      int ci = tid >> 2, ch = tid & 3;
      if (ci < candN) {
        uint64_t kc = s_cand[ci];
        int lo = (F * ch) >> 2, hi = (F * (ch + 1)) >> 2;
        int cnt = 0;
        for (int j = lo; j < hi; ++j) cnt += (s_key[j] < kc) ? 1 : 0;
        atomicAdd(&s_crank[ci], cnt);
      }
      __syncthreads();
      if (tid < candN && tid < CANDMAX) {
        int r = s_crank[tid];
        if (r < FGPER) s_ford[r] = (unsigned short)(s_cand[tid] & 0xFFFFull);
      }
    } else {
      // paranoia fallback: full stable rank
      for (int i = tid; i < F; i += BLOCK) {
        uint64_t ki = s_key[i];
        int r = 0;
        for (int j = 0; j < F; ++j) r += (s_key[j] < ki) ? 1 : 0;
        s_ford[r] = (unsigned short)(ki & 0xFFFFull);
      }
    }
  } else {
    // Bc==0 (never for this data): need full fg order
    for (int i = tid; i < F; i += BLOCK) {
      uint64_t ki = s_key[i];
      int r = 0;
      for (int j = 0; j < F; ++j) r += (s_key[j] < ki) ? 1 : 0;
      s_ford[r] = (unsigned short)(ki & 0xFFFFull);
    }
  }
  __syncthreads();

  // ---- sampling + bbox transform + output ----
  if (tid < ROUT) {
    const int j = tid;
    float rfg = u01f(tf_bits32(kr0, kr1, (uint32_t)j));   // uniform(kr,(R,))
    float rbg = u01f(tf_bits32(kb0, kb1, (uint32_t)j));   // uniform(kb,(R,))

    int fg_this = (Bc > 0) ? (F < FGPER ? F : FGPER) : ((F > 0) ? ROUT : 0);
    int keep; float lab;
    if (j < fg_this) {
      int p;
      if (j < F) { p = j; }
      else {
        p = (int)(__fmul_rn(rfg, (float)(F < 1 ? 1 : F)));  // trunc like astype(int32)
        if (p > NT - 1) p = NT - 1;
        if (p < 0) p = 0;
      }
      keep = (p < F) ? (int)s_ford[p] : nth_non(mvp, p - F, 0);
      lab = s_glb[agp[keep]];
    } else {
      int q = (int)(__fmul_rn(rbg, (float)(Bc < 1 ? 1 : Bc)));
      if (q > NT - 1) q = NT - 1;
      if (q < 0) q = 0;
      if (Bc > 0) keep = (q < Bc) ? (int)s_bidx[q] : nth_non(mvp, q - Bc, 1);
      else        keep = q;   // no bg: argsort of all-2.0 is identity
      lab = 0.0f;
    }

    float ex1, ey1, ex2, ey2;
    if (keep < NROI) {
      const float* p = all_rois + ((size_t)b * NROI + keep) * 5;
      ex1 = p[1]; ey1 = p[2]; ex2 = p[3]; ey2 = p[4];
    } else {
      int k = keep - NROI;
      ex1 = s_gx1[k]; ey1 = s_gy1[k]; ex2 = s_gx2[k]; ey2 = s_gy2[k];
    }
    int ga = agp[keep];
    float gx1 = s_gx1[ga], gy1 = s_gy1[ga], gx2 = s_gx2[ga], gy2 = s_gy2[ga];

    float ew = ex2 - ex1 + 1.0f, eh = ey2 - ey1 + 1.0f;
    float ecx = ex1 + 0.5f * ew, ecy = ey1 + 0.5f * eh;
    float gw = gx2 - gx1 + 1.0f, gh = gy2 - gy1 + 1.0f;
    float gcx = gx1 + 0.5f * gw, gcy = gy1 + 0.5f * gh;
    float tt[4];
    tt[0] = (gcx - ecx) / ew;
    tt[1] = (gcy - ecy) / eh;
    tt[2] = logf(gw / ew);
    tt[3] = logf(gh / eh);
    bool isfg = (lab > 0.0f);

    size_t roff = (size_t)b * ROUT + j;
    float* po = out + roff * 5;
    po[0] = (float)b; po[1] = ex1; po[2] = ey1; po[3] = ex2; po[4] = ey2;
    out[(size_t)NB * ROUT * 5 + roff] = lab;
    float* pt = out + (size_t)NB * ROUT * 6 + roff * 4;
    float* pi = out + (size_t)NB * ROUT * 10 + roff * 4;
    float* pq = out + (size_t)NB * ROUT * 14 + roff * 4;
    for (int c = 0; c < 4; ++c) {
      float tn = (tt[c] - bmeans[c]) / bstds[c];
      float vi = isfg ? binw[c] : 0.0f;
      pt[c] = isfg ? tn : 0.0f;
      pi[c] = vi;
      pq[c] = (vi > 0.0f) ? 1.0f : 0.0f;
    }
  }
}

extern "C" void kernel_launch(void* const* d_in, const int* in_sizes, int n_in,
                              void* d_out, int out_size, void* d_ws, size_t ws_size,
                              hipStream_t stream) {
  const float* all_rois = (const float*)d_in[0];
  const float* gt_boxes = (const float*)d_in[1];
  // d_in[2] = num_boxes (unused, as in the reference)
  const float* bmeans = (const float*)d_in[3];
  const float* bstds  = (const float*)d_in[4];
  const float* binw   = (const float*)d_in[5];
  float* out = (float*)d_out;

  float* maxov_ws = (float*)d_ws;                                        // NB*NT f32
  unsigned char* asg_ws = (unsigned char*)(maxov_ws + (size_t)NB * NT);  // NB*NT u8

  iou_kernel<<<dim3(NCHA, NB), dim3(BLOCKA), 0, stream>>>(all_rois, gt_boxes, maxov_ws, asg_ws);
  sample_kernel<<<dim3(NB), dim3(BLOCK), 0, stream>>>(all_rois, gt_boxes, maxov_ws, asg_ws,
                                                      bmeans, bstds, binw, out);
}

// Round 7
// 112.815 us; speedup vs baseline: 2.4464x; 1.0228x over previous
//
#include <hip/hip_runtime.h>
#include <stdint.h>

#define NB    64      // batch
#define NROI  6000    // proposals per image
#define KGT   100     // gt slots per image
#define NT    6100    // NROI + KGT
#define ROUT  256     // sampled rois per image
#define FGPER 64

#define BLOCKA 256                      // iou block
#define ROIS_PER_BLOCK (BLOCKA * 2)     // 2 rois per thread
#define NCHA ((NT + ROIS_PER_BLOCK - 1) / ROIS_PER_BLOCK)   // 12

#define BLOCK 512
#define NWAVE (BLOCK / 64)
#define SEG 96                 // ceil(6100/64) = 96 segments of 64
#define SEGW (SEG / NWAVE)     // 12 segments per wave
#define CANDMAX 128

// class encoding in ws u16: (cls << 8) | gt_assign ; cls: 2=fg, 1=bg, 0=neg(-1 row)
#define CLS_FG 2
#define CLS_BG 1
#define CLS_NEG 0

__device__ __forceinline__ uint32_t rotl32(uint32_t v, int s) { return (v << s) | (v >> (32 - s)); }

// Exact replica of JAX threefry2x32 (20 rounds)
#define TFR(r) { x0 += x1; x1 = rotl32(x1, r); x1 ^= x0; }
__device__ __forceinline__ void tf2x32(uint32_t k0, uint32_t k1, uint32_t& x0, uint32_t& x1) {
  uint32_t k2 = k0 ^ k1 ^ 0x1BD11BDAu;
  x0 += k0; x1 += k1;
  TFR(13) TFR(15) TFR(26) TFR(6)
  x0 += k1; x1 += k2 + 1u;
  TFR(17) TFR(29) TFR(16) TFR(24)
  x0 += k2; x1 += k0 + 2u;
  TFR(13) TFR(15) TFR(26) TFR(6)
  x0 += k0; x1 += k1 + 3u;
  TFR(17) TFR(29) TFR(16) TFR(24)
  x0 += k1; x1 += k2 + 4u;
  TFR(13) TFR(15) TFR(26) TFR(6)
  x0 += k2; x1 += k0 + 5u;
}

// jax_threefry_partitionable=True (default since JAX 0.4.36):
// bits for flat index i = fold(TF(key, (0, i))) = out0 ^ out1
__device__ __forceinline__ uint32_t tf_bits32(uint32_t k0, uint32_t k1, uint32_t idx) {
  uint32_t x0 = 0u, x1 = idx;
  tf2x32(k0, k1, x0, x1);
  return x0 ^ x1;
}

// JAX uniform [0,1): bitcast(bits>>9 | 0x3F800000) - 1.0
__device__ __forceinline__ float u01f(uint32_t bits) {
  return __uint_as_float((bits >> 9) | 0x3F800000u) - 1.0f;
}

// ============================ kernel A: IoU max/argmax ============================
// grid (NCHA, NB) x BLOCKA, 2 rois/thread. Writes (cls<<8|asg) u16 per roi to ws.
__global__ __launch_bounds__(BLOCKA) void iou_kernel(
    const float* __restrict__ all_rois,   // [NB, NROI, 5]
    const float* __restrict__ gt_boxes,   // [NB, KGT, 5]
    unsigned short* __restrict__ cls_ws)  // [NB, NT]
{
#pragma clang fp contract(off)
  __shared__ float s_gx1[KGT], s_gy1[KGT], s_gx2[KGT], s_gy2[KGT];   // original order (appended rois)
  __shared__ float s_cx1[KGT], s_cy1[KGT], s_cx2[KGT], s_cy2[KGT], s_car[KGT];  // compacted valid
  __shared__ short s_ck[KGT];
  __shared__ unsigned long long s_zm[2];
  __shared__ int s_V, s_minz;

  const int b = blockIdx.y;
  const int tid = threadIdx.x;
  const int lane = tid & 63, wv = tid >> 6;

  bool nz = false;
  float gx1v = 0, gy1v = 0, gx2v = 0, gy2v = 0, garv = 0;
  if (tid < KGT) {
    const float* g = gt_boxes + ((size_t)b * KGT + tid) * 5;
    gx1v = g[0]; gy1v = g[1]; gx2v = g[2]; gy2v = g[3];
    s_gx1[tid] = gx1v; s_gy1[tid] = gy1v; s_gx2[tid] = gx2v; s_gy2[tid] = gy2v;
    float wg = __fadd_rn(__fadd_rn(gx2v, -gx1v), 1.0f);
    float hg = __fadd_rn(__fadd_rn(gy2v, -gy1v), 1.0f);
    garv = __fmul_rn(wg, hg);
    nz = !(wg == 1.0f && hg == 1.0f);
  }
  if (wv < 2) {
    unsigned long long bm = __ballot(nz);
    if (lane == 0) s_zm[wv] = bm;
  }
  __syncthreads();
  if (tid == 0) {
    unsigned long long z0 = s_zm[0], z1 = s_zm[1];
    unsigned long long g0 = ~z0;                                   // zero-rows among k=0..63
    unsigned long long g1 = (~z1) & ((1ull << (KGT - 64)) - 1ull); // k=64..99
    int mz = -1;
    if (g0) mz = __ffsll((long long)g0) - 1;
    else if (g1) mz = 64 + __ffsll((long long)g1) - 1;
    s_minz = mz;
    s_V = __popcll(z0) + __popcll(z1);
  }
  if (tid < KGT && nz) {
    unsigned long long lm = (1ull << lane) - 1ull;
    int pos = (wv == 0) ? __popcll(s_zm[0] & lm)
                        : __popcll(s_zm[0]) + __popcll(s_zm[1] & lm);
    s_cx1[pos] = gx1v; s_cy1[pos] = gy1v; s_cx2[pos] = gx2v; s_cy2[pos] = gy2v;
    s_car[pos] = garv; s_ck[pos] = (short)tid;
  }
  __syncthreads();
  const int V = s_V, minz = s_minz;

  const int base = blockIdx.x * ROIS_PER_BLOCK;
  const int t0 = base + tid, t1 = base + BLOCKA + tid;

  // load two rois (guarded)
  float x1a, y1a, x2a, y2a, x1b, y1b, x2b, y2b;
  {
    int ta = (t0 < NT) ? t0 : 0;
    if (ta < NROI) {
      const float* p = all_rois + ((size_t)b * NROI + ta) * 5;
      x1a = p[1]; y1a = p[2]; x2a = p[3]; y2a = p[4];
    } else {
      int k = ta - NROI;
      x1a = s_gx1[k]; y1a = s_gy1[k]; x2a = s_gx2[k]; y2a = s_gy2[k];
    }
    int tb = (t1 < NT) ? t1 : 0;
    if (tb < NROI) {
      const float* p = all_rois + ((size_t)b * NROI + tb) * 5;
      x1b = p[1]; y1b = p[2]; x2b = p[3]; y2b = p[4];
    } else {
      int k = tb - NROI;
      x1b = s_gx1[k]; y1b = s_gy1[k]; x2b = s_gx2[k]; y2b = s_gy2[k];
    }
  }
  float wra = __fadd_rn(__fadd_rn(x2a, -x1a), 1.0f);
  float hra = __fadd_rn(__fadd_rn(y2a, -y1a), 1.0f);
  float ara = __fmul_rn(wra, hra);
  bool rza = (wra == 1.0f && hra == 1.0f);
  float wrb = __fadd_rn(__fadd_rn(x2b, -x1b), 1.0f);
  float hrb = __fadd_rn(__fadd_rn(y2b, -y1b), 1.0f);
  float arb = __fmul_rn(wrb, hrb);
  bool rzb = (wrb == 1.0f && hrb == 1.0f);

  float besta = -2.0f, bestb = -2.0f;
  int bva = -1, bvb = -1;            // compacted index of current argmax

#define IOU_STEP(vv)                                                              \
  {                                                                               \
    float cx1 = s_cx1[vv], cy1 = s_cy1[vv], cx2 = s_cx2[vv], cy2 = s_cy2[vv];     \
    float car = s_car[vv];                                                        \
    {                                                                             \
      float iw = __fadd_rn(__fadd_rn(fminf(x2a, cx2), -fmaxf(x1a, cx1)), 1.0f);   \
      iw = fmaxf(iw, 0.0f);                                                       \
      float ih = __fadd_rn(__fadd_rn(fminf(y2a, cy2), -fmaxf(y1a, cy1)), 1.0f);   \
      ih = fmaxf(ih, 0.0f);                                                       \
      float inter = __fmul_rn(iw, ih);                                            \
      float ov = inter / __fadd_rn(__fadd_rn(ara, car), -inter);                  \
      if (ov > besta) { besta = ov; bva = (vv); }                                 \
    }                                                                             \
    {                                                                             \
      float iw = __fadd_rn(__fadd_rn(fminf(x2b, cx2), -fmaxf(x1b, cx1)), 1.0f);   \
      iw = fmaxf(iw, 0.0f);                                                       \
      float ih = __fadd_rn(__fadd_rn(fminf(y2b, cy2), -fmaxf(y1b, cy1)), 1.0f);   \
      ih = fmaxf(ih, 0.0f);                                                       \
      float inter = __fmul_rn(iw, ih);                                            \
      float ov = inter / __fadd_rn(__fadd_rn(arb, car), -inter);                  \
      if (ov > bestb) { bestb = ov; bvb = (vv); }                                 \
    }                                                                             \
  }

  int v = 0;
  for (; v + 1 < V; v += 2) { IOU_STEP(v) IOU_STEP(v + 1) }
  if (v < V) IOU_STEP(v)
#undef IOU_STEP

  int bka = (bva >= 0) ? (int)s_ck[bva] : 0;
  int bkb = (bvb >= 0) ? (int)s_ck[bvb] : 0;
  // zero-gt fold (value exactly 0.0 at orig indices >= minz) + roi_zero override
  if (rza) { besta = -1.0f; bka = 0; }
  else {
    if (besta < 0.0f) { besta = 0.0f; bka = (minz >= 0 ? minz : 0); }
    else if (besta == 0.0f && minz >= 0 && minz < bka) bka = minz;
  }
  if (rzb) { bestb = -1.0f; bkb = 0; }
  else {
    if (bestb < 0.0f) { bestb = 0.0f; bkb = (minz >= 0 ? minz : 0); }
    else if (bestb == 0.0f && minz >= 0 && minz < bkb) bkb = minz;
  }
  int clsa = (besta >= 0.5f) ? CLS_FG : ((besta >= 0.0f) ? CLS_BG : CLS_NEG);
  int clsb = (bestb >= 0.5f) ? CLS_FG : ((bestb >= 0.0f) ? CLS_BG : CLS_NEG);
  if (t0 < NT) cls_ws[(size_t)b * NT + t0] = (unsigned short)((clsa << 8) | bka);
  if (t1 < NT) cls_ws[(size_t)b * NT + t1] = (unsigned short)((clsb << 8) | bkb);
}

// p-th (0-based) index t whose mask is FALSE, ascending (argsort 2.0-pad region). Never hot.
// mode 0: member = fg; mode 1: member = bg.
__device__ int nth_non(const unsigned short* cp, int n, int mode) {
  int c = 0;
  for (int t = 0; t < NT; ++t) {
    int cls = cp[t] >> 8;
    bool member = (mode == 0) ? (cls == CLS_FG) : (cls == CLS_BG);
    if (!member) { if (c == n) return t; ++c; }
  }
  return NT - 1;
}

// ====================== kernel B: compaction + select + sampling ======================
__global__ __launch_bounds__(BLOCK) void sample_kernel(
    const float* __restrict__ all_rois,
    const float* __restrict__ gt_boxes,
    const unsigned short* __restrict__ cls_ws,
    const float* __restrict__ bmeans,
    const float* __restrict__ bstds,
    const float* __restrict__ binw,
    float* __restrict__ out)
{
#pragma clang fp contract(off)
  __shared__ float s_gx1[KGT], s_gy1[KGT], s_gx2[KGT], s_gy2[KGT], s_glb[KGT];
  __shared__ uint64_t s_key[NT];            // fg keys, index-ordered
  __shared__ unsigned short s_bidx[NT];     // bg indices, ascending
  __shared__ unsigned short s_ford[NT];     // rank -> roi index (only r<64 used on hot path)
  __shared__ int s_cf[SEG], s_cb[SEG];
  __shared__ int s_pf[SEG + 1], s_pb[SEG + 1];
  __shared__ int s_hist[512];
  __shared__ int s_wtot[NWAVE];
  __shared__ uint64_t s_cand[CANDMAX];
  __shared__ int s_crank[CANDMAX];
  __shared__ int s_candN;

  const int b = blockIdx.x;
  const int tid = threadIdx.x;
  const int lane = tid & 63, wv = tid >> 6;
  const unsigned short* cp = cls_ws + (size_t)b * NT;

  if (tid < KGT) {
    const float* g = gt_boxes + ((size_t)b * KGT + tid) * 5;
    s_gx1[tid] = g[0]; s_gy1[tid] = g[1]; s_gx2[tid] = g[2]; s_gy2[tid] = g[3]; s_glb[tid] = g[4];
  }
  s_hist[tid] = 0;                      // BLOCK == 512 exactly
  if (tid < CANDMAX) s_crank[tid] = 0;
  if (tid == 0) s_candN = 0;

  // per-image keys (partitionable threefry):
  // keys[b] = TF((0,42),(0,b)); kf,kb,kr = TF(keys[b],(0,{0,1,2}))
  uint32_t kk0 = 0u, kk1 = (uint32_t)b;
  tf2x32(0u, 42u, kk0, kk1);
  uint32_t kf0 = 0u, kf1 = 0u; tf2x32(kk0, kk1, kf0, kf1);
  uint32_t kb0 = 0u, kb1 = 1u; tf2x32(kk0, kk1, kb0, kb1);
  uint32_t kr0 = 0u, kr1 = 2u; tf2x32(kk0, kk1, kr0, kr1);

  // ---- pass 1: per-segment fg/bg counts (no barriers inside) ----
  int fgbits = 0, bgbits = 0;
#pragma unroll
  for (int i = 0; i < SEGW; ++i) {
    int s = i * NWAVE + wv;
    int t = s * 64 + lane;
    int cls = (t < NT) ? (cp[t] >> 8) : -1;
    bool fg = (cls == CLS_FG);
    bool bg = (cls == CLS_BG);
    unsigned long long bf = __ballot(fg), bb = __ballot(bg);
    if (lane == 0) { s_cf[s] = __popcll(bf); s_cb[s] = __popcll(bb); }
    fgbits |= fg ? (1 << i) : 0;
    bgbits |= bg ? (1 << i) : 0;
  }
  __syncthreads();

  // ---- pass 2: exclusive scan of segment counts (wave 0: fg, wave 1: bg) ----
  if (wv < 2) {
    int* src = (wv == 0) ? s_cf : s_cb;
    int* dst = (wv == 0) ? s_pf : s_pb;
    int v0 = src[lane];
    int v1 = (lane < SEG - 64) ? src[64 + lane] : 0;
    int x = v0;
    for (int off = 1; off < 64; off <<= 1) { int n = __shfl_up(x, off); if (lane >= off) x += n; }
    int tot0 = __shfl(x, 63);
    int y = v1;
    for (int off = 1; off < 32; off <<= 1) { int n = __shfl_up(y, off); if (lane >= off) y += n; }
    int tot96 = tot0 + __shfl(y, 31);
    dst[lane] = x - v0;
    if (lane < SEG - 64) dst[64 + lane] = tot0 + (y - v1);
    if (lane == 0) dst[SEG] = tot96;
  }
  __syncthreads();
  const int F = s_pf[SEG], Bc = s_pb[SEG];

  // ---- pass 3: positioned writes (fg keys with threefry bits; bg indices) ----
#pragma unroll
  for (int i = 0; i < SEGW; ++i) {
    int s = i * NWAVE + wv;
    int t = s * 64 + lane;
    bool fg = (fgbits >> i) & 1, bg = (bgbits >> i) & 1;
    unsigned long long bf = __ballot(fg), bb = __ballot(bg);
    unsigned long long lm = (1ull << lane) - 1ull;
    if (fg) {
      uint32_t ub = tf_bits32(kf0, kf1, (uint32_t)t);   // uniform(kf,(NT,)) bits[t]
      s_key[s_pf[s] + __popcll(bf & lm)] = (((uint64_t)(ub >> 9)) << 32) | (uint32_t)t;
    }
    if (bg) s_bidx[s_pb[s] + __popcll(bb & lm)] = (unsigned short)t;
  }
  __syncthreads();

  // ---- rank-select: only ranks < 64 are read when Bc>0 (always true here) ----
  if (Bc > 0) {
    // histogram on top-9 random bits (key bits 54..46)
    for (int i = tid; i < F; i += BLOCK)
      atomicAdd(&s_hist[(int)(s_key[i] >> 46) & 511], 1);
    __syncthreads();
    // exclusive scan of 512 buckets (8 waves of 64 + cross-wave offsets)
    int hv = s_hist[wv * 64 + lane];
    int hx = hv;
    for (int off = 1; off < 64; off <<= 1) { int n = __shfl_up(hx, off); if (lane >= off) hx += n; }
    if (lane == 63) s_wtot[wv] = hx;
    __syncthreads();
    int woff = 0;
    for (int w = 0; w < wv; ++w) woff += s_wtot[w];
    s_hist[wv * 64 + lane] = woff + hx - hv;   // in-place: now cum[bucket]
    __syncthreads();
    // candidates: keys in buckets with cum < 64
    for (int i = tid; i < F; i += BLOCK) {
      uint64_t k = s_key[i];
      if (s_hist[(int)(k >> 46) & 511] < FGPER) {
        int pos = atomicAdd(&s_candN, 1);
        if (pos < CANDMAX) s_cand[pos] = k;
      }
    }
    __syncthreads();
    int candN = s_candN;
    if (candN <= CANDMAX) {
      // exact global rank per candidate (4 threads per candidate)
      int ci = tid >> 2, ch = tid & 3;
      if (ci < candN) {
        uint64_t kc = s_cand[ci];
        int lo = (F * ch) >> 2, hi = (F * (ch + 1)) >> 2;
        int cnt = 0;
        for (int j = lo; j < hi; ++j) cnt += (s_key[j] < kc) ? 1 : 0;
        atomicAdd(&s_crank[ci], cnt);
      }
      __syncthreads();
      if (tid < candN && tid < CANDMAX) {
        int r = s_crank[tid];
        if (r < FGPER) s_ford[r] = (unsigned short)(s_cand[tid] & 0xFFFFull);
      }
    } else {
      // paranoia fallback: full stable rank
      for (int i = tid; i < F; i += BLOCK) {
        uint64_t ki = s_key[i];
        int r = 0;
        for (int j = 0; j < F; ++j) r += (s_key[j] < ki) ? 1 : 0;
        s_ford[r] = (unsigned short)(ki & 0xFFFFull);
      }
    }
  } else {
    // Bc==0 (never for this data): need full fg order
    for (int i = tid; i < F; i += BLOCK) {
      uint64_t ki = s_key[i];
      int r = 0;
      for (int j = 0; j < F; ++j) r += (s_key[j] < ki) ? 1 : 0;
      s_ford[r] = (unsigned short)(ki & 0xFFFFull);
    }
  }
  __syncthreads();

  // ---- sampling + bbox transform + output ----
  if (tid < ROUT) {
    const int j = tid;
    float rfg = u01f(tf_bits32(kr0, kr1, (uint32_t)j));   // uniform(kr,(R,))
    float rbg = u01f(tf_bits32(kb0, kb1, (uint32_t)j));   // uniform(kb,(R,))

    int fg_this = (Bc > 0) ? (F < FGPER ? F : FGPER) : ((F > 0) ? ROUT : 0);
    int keep; float lab;
    if (j < fg_this) {
      int p;
      if (j < F) { p = j; }
      else {
        p = (int)(__fmul_rn(rfg, (float)(F < 1 ? 1 : F)));  // trunc like astype(int32)
        if (p > NT - 1) p = NT - 1;
        if (p < 0) p = 0;
      }
      keep = (p < F) ? (int)s_ford[p] : nth_non(cp, p - F, 0);
      lab = s_glb[cp[keep] & 0xFF];
    } else {
      int q = (int)(__fmul_rn(rbg, (float)(Bc < 1 ? 1 : Bc)));
      if (q > NT - 1) q = NT - 1;
      if (q < 0) q = 0;
      if (Bc > 0) keep = (q < Bc) ? (int)s_bidx[q] : nth_non(cp, q - Bc, 1);
      else        keep = q;   // no bg: argsort of all-2.0 is identity
      lab = 0.0f;
    }

    float ex1, ey1, ex2, ey2;
    if (keep < NROI) {
      const float* p = all_rois + ((size_t)b * NROI + keep) * 5;
      ex1 = p[1]; ey1 = p[2]; ex2 = p[3]; ey2 = p[4];
    } else {
      int k = keep - NROI;
      ex1 = s_gx1[k]; ey1 = s_gy1[k]; ex2 = s_gx2[k]; ey2 = s_gy2[k];
    }
    int ga = cp[keep] & 0xFF;
    float gx1 = s_gx1[ga], gy1 = s_gy1[ga], gx2 = s_gx2[ga], gy2 = s_gy2[ga];

    float ew = ex2 - ex1 + 1.0f, eh = ey2 - ey1 + 1.0f;
    float ecx = ex1 + 0.5f * ew, ecy = ey1 + 0.5f * eh;
    float gw = gx2 - gx1 + 1.0f, gh = gy2 - gy1 + 1.0f;
    float gcx = gx1 + 0.5f * gw, gcy = gy1 + 0.5f * gh;
    float tt[4];
    tt[0] = (gcx - ecx) / ew;
    tt[1] = (gcy - ecy) / eh;
    tt[2] = logf(gw / ew);
    tt[3] = logf(gh / eh);
    bool isfg = (lab > 0.0f);

    size_t roff = (size_t)b * ROUT + j;
    float* po = out + roff * 5;
    po[0] = (float)b; po[1] = ex1; po[2] = ey1; po[3] = ex2; po[4] = ey2;
    out[(size_t)NB * ROUT * 5 + roff] = lab;
    float* pt = out + (size_t)NB * ROUT * 6 + roff * 4;
    float* pi = out + (size_t)NB * ROUT * 10 + roff * 4;
    float* pq = out + (size_t)NB * ROUT * 14 + roff * 4;
    for (int c = 0; c < 4; ++c) {
      float tn = (tt[c] - bmeans[c]) / bstds[c];
      float vi = isfg ? binw[c] : 0.0f;
      pt[c] = isfg ? tn : 0.0f;
      pi[c] = vi;
      pq[c] = (vi > 0.0f) ? 1.0f : 0.0f;
    }
  }
}

extern "C" void kernel_launch(void* const* d_in, const int* in_sizes, int n_in,
                              void* d_out, int out_size, void* d_ws, size_t ws_size,
                              hipStream_t stream) {
  const float* all_rois = (const float*)d_in[0];
  const float* gt_boxes = (const float*)d_in[1];
  // d_in[2] = num_boxes (unused, as in the reference)
  const float* bmeans = (const float*)d_in[3];
  const float* bstds  = (const float*)d_in[4];
  const float* binw   = (const float*)d_in[5];
  float* out = (float*)d_out;

  unsigned short* cls_ws = (unsigned short*)d_ws;   // NB*NT u16

  iou_kernel<<<dim3(NCHA, NB), dim3(BLOCKA), 0, stream>>>(all_rois, gt_boxes, cls_ws);
  sample_kernel<<<dim3(NB), dim3(BLOCK), 0, stream>>>(all_rois, gt_boxes, cls_ws,
                                                      bmeans, bstds, binw, out);
}